// Round 17
// baseline (601.270 us; speedup 1.0000x reference)
//
#include <hip/hip_runtime.h>
#include <hip/hip_bf16.h>

#define NN 50000
#define EE 800000
#define GG 64
#define LL 3
#define CC 4
#define HH 64
#define BN_EPS 1e-5f
#define NSHADOW 4
#define SBLK 196          // ceil(NN/256) node-parallel blocks
#define GIN_BLOCKS 2048   // grid-stride gather kernels (8192 waves)
#define MM_BLOCKS 256     // MFMA C kernel (1024 waves >= 782 tiles)
#define ECHUNKS 3125      // ceil(EE/256)
#define NODE_RANGE 6250   // NN/8, dst-range binning for k_fill

// NOTE: harness passes ALL integer inputs as int32 (edge_index/batch included).
// NOTE: cooperative launch + grid.sync 4x SLOWER than kernel barriers (R5).
// NOTE: single-block k_final 90us latency-bound -> final MLP split (R7).
// NOTE: multi-node-per-wave gather serializes latency chains (R7/R12); tile-barrier
//       gather+lin1 fusion couples waves to slowest node (R15: +9us) — R17 fuses
//       lin1 per-wave instead: broadcast row into all-16-rows-identical A-frag
//       (16 shfl, no barrier), 8 MFMA, take row 0. No cross-wave coupling.
// NOTE: R11: GIN kernels are VALU-ISSUE bound; readlane broadcasts 745->646us.
// NOTE: R13: MLPs on MFMA 16x16x32 bf16: 654->563us.
//       Fragment layouts: A[m=lane&15][k=quad*8+j]; C/D[col=lane&15][row=quad*4+reg].
// NOTE: R14: range-major binned k_fill 51->46us — near floor for atomic scatter.
// NOTE: R16: 4x gather MLP (32 rows in flight) neutral -> gather is at a
//       latency/fabric floor, not issue-bound; 16 rows in flight suffices.

typedef __attribute__((ext_vector_type(8))) short bf16x8;
typedef __attribute__((ext_vector_type(4))) float f32x4;

__device__ __forceinline__ float bf2f(short s) {
    return __int_as_float(((int)(unsigned short)s) << 16);
}
__device__ __forceinline__ short f2bf(float v) {
    __hip_bfloat16 hb = __float2bfloat16(v);
    return *(short*)&hb;
}

// ---------------- setup kernels ----------------

// fused: x fp32->bf16 convert + degree count + cluster histogram + W-fragment pack.
__global__ void k_deghist(const int* __restrict__ dst, int* __restrict__ deg,
                          const int* __restrict__ labels, int* __restrict__ blockcnt,
                          const float* __restrict__ x_in, __hip_bfloat16* __restrict__ xw,
                          const float* __restrict__ W1, const float* __restrict__ W2,
                          short* __restrict__ wf) {
    __shared__ int cnt[CC];
    int tid = threadIdx.x;
    for (int i = blockIdx.x * 256 + tid; i < NN * 64; i += gridDim.x * 256)
        xw[i] = __float2bfloat16(x_in[i]);
    // W pack: first 384 blocks, one element per thread (24*4096 = 98304)
    int o = blockIdx.x * 256 + tid;
    if (o < 24 * 4096) {
        int m = o >> 12;
        int r = o & 4095;
        int colt = r >> 10;
        int fragk = (r >> 9) & 1;
        int lane = (r >> 3) & 63;
        int j = r & 7;
        int k = fragk * 32 + ((lane >> 4) << 3) + j;
        int n = colt * 16 + (lane & 15);
        const float* src = (m < 12) ? (W1 + (size_t)m * 4096) : (W2 + (size_t)(m - 12) * 4096);
        wf[o] = f2bf(src[k * 64 + n]);
    }
    bool hist = (blockIdx.x < SBLK);
    if (hist && tid < CC) cnt[tid] = 0;
    __syncthreads();
    int gid = blockIdx.x * 256 + tid;
    if (gid < EE) atomicAdd(&deg[dst[gid]], 1);
    if (hist && gid < NN) atomicAdd(&cnt[labels[gid]], 1);
    __syncthreads();
    if (hist && tid < CC) blockcnt[tid * SBLK + blockIdx.x] = cnt[tid];
}

__global__ __launch_bounds__(256) void k_scancombo(
    const int* __restrict__ deg, int* __restrict__ rowptr, int* __restrict__ dpart,
    const int* __restrict__ blockcnt, int* __restrict__ coffs, int* __restrict__ ccount) {
    __shared__ int smem[CC * 256];
    int tid = threadIdx.x;
    if (blockIdx.x < SBLK) {
        int i = blockIdx.x * 256 + tid;
        int v = (i < NN) ? deg[i] : 0;
        smem[tid] = v;
        __syncthreads();
        for (int off = 1; off < 256; off <<= 1) {
            int u = (tid >= off) ? smem[tid - off] : 0;
            __syncthreads();
            smem[tid] += u;
            __syncthreads();
        }
        if (i < NN) rowptr[i] = smem[tid] - v;  // local exclusive
        if (tid == 255) dpart[blockIdx.x] = smem[255];
    } else {
        int own[CC];
        for (int c = 0; c < CC; c++) {
            own[c] = (tid < SBLK) ? blockcnt[c * SBLK + tid] : 0;
            smem[c * 256 + tid] = own[c];
        }
        __syncthreads();
        for (int off = 1; off < 256; off <<= 1) {
            int v[CC];
            for (int c = 0; c < CC; c++) v[c] = (tid >= off) ? smem[c * 256 + tid - off] : 0;
            __syncthreads();
            for (int c = 0; c < CC; c++) smem[c * 256 + tid] += v[c];
            __syncthreads();
        }
        if (tid < SBLK)
            for (int c = 0; c < CC; c++) coffs[c * SBLK + tid] = smem[c * 256 + tid] - own[c];
        if (tid == 0)
            for (int c = 0; c < CC; c++) ccount[c] = smem[c * 256 + 255];
    }
}

__global__ __launch_bounds__(256) void k_dscan2(int* __restrict__ dpart,
                                                int* __restrict__ dbase,
                                                int* __restrict__ rowptr) {
    __shared__ int s[256];
    int tid = threadIdx.x;
    int v = (tid < SBLK) ? dpart[tid] : 0;
    s[tid] = v;
    __syncthreads();
    for (int off = 1; off < 256; off <<= 1) {
        int u = (tid >= off) ? s[tid - off] : 0;
        __syncthreads();
        s[tid] += u;
        __syncthreads();
    }
    if (tid < SBLK) dbase[tid] = s[tid] - v;
    if (tid == 0) rowptr[NN] = EE;
}

__global__ __launch_bounds__(256) void k_cfill_dscan3(
    int* __restrict__ rowptr, const int* __restrict__ dbase, int* __restrict__ cursor,
    const int* __restrict__ labels, const int* __restrict__ coffs, int* __restrict__ clist) {
    __shared__ int pos[CC];
    int tid = threadIdx.x;
    if (tid < CC) pos[tid] = coffs[tid * SBLK + blockIdx.x];
    __syncthreads();
    int i = blockIdx.x * 256 + tid;
    if (i < NN) {
        int r = rowptr[i] + dbase[blockIdx.x];
        rowptr[i] = r;
        cursor[i] = r;
        int c = labels[i];
        int p = atomicAdd(&pos[c], 1);
        clist[c * NN + p] = i;
    }
}

// RANGE-MAJOR binned CSR fill (R14). adj stores BYTE offsets: src<<7.
__global__ void k_fill(const int* __restrict__ src, const int* __restrict__ dst,
                       int* __restrict__ cursor, int* __restrict__ adj) {
    int range = blockIdx.x / ECHUNKS;
    int e = (blockIdx.x - range * ECHUNKS) * 256 + threadIdx.x;
    if (e < EE) {
        int d = dst[e];
        int lo = range * NODE_RANGE;
        if (d >= lo && d < lo + NODE_RANGE) {
            int pos = atomicAdd(&cursor[d], 1);
            adj[pos] = src[e] << 7;
        }
    }
}

// ---------------- fused gather + per-wave MFMA Lin1 (R17) ----------------
// 1 node/wave. Gather: 4 lane-groups x 8B/lane = 4 rows/issue, 4 chains
// (16 rows in flight). Then lin1 per-wave: broadcast the reduced row into an
// A-fragment with all 16 m-rows identical (16 shfl, no LDS/barrier), 8 MFMA
// vs resident W1 frags, row 0 from lanes 0-15, +bias, store h1, BN partials.
// Optional fused pool of previous layer (tpool >= 0).
__global__ __launch_bounds__(256) void k_gl1(
    const __hip_bfloat16* __restrict__ xw, const int* __restrict__ adj,
    const int* __restrict__ rowptr, const int* __restrict__ clist_c,
    const int* __restrict__ ccount_c, const short* __restrict__ wf1,
    const float* __restrict__ b1c, __hip_bfloat16* __restrict__ h1buf,
    float* __restrict__ bnacc,
    const int* __restrict__ batch, float* __restrict__ z, int tpool) {
    __shared__ float lds_red[4][128];
    int cnt = *ccount_c;
    int lane = threadIdx.x & 63;
    int wave = threadIdx.x >> 6;
    int wid = blockIdx.x * 4 + wave;
    int nwaves = gridDim.x * 4;
    int grp = lane >> 4;   // 0..3
    int l16 = lane & 15;
    const char* xwb = (const char*)xw;

    bf16x8 wb[8];
    #pragma unroll
    for (int f = 0; f < 8; f++)
        wb[f] = *(const bf16x8*)(wf1 + f * 512 + lane * 8);
    float bcol[4];
    #pragma unroll
    for (int colt = 0; colt < 4; colt++) bcol[colt] = b1c[colt * 16 + l16];

    float sS[4] = {0.f, 0.f, 0.f, 0.f};
    float sQ[4] = {0.f, 0.f, 0.f, 0.f};

    int idx = wid;
    int node_next = (idx < cnt) ? clist_c[idx] : 0;
    for (; idx < cnt; idx += nwaves) {
        int node = node_next;
        int nidx = idx + nwaves;
        if (nidx < cnt) node_next = clist_c[nidx];  // prefetch next node id
        int rb = rowptr[node], re = rowptr[node + 1];
        float ax[4], ay[4], az[4], aw[4];
        #pragma unroll
        for (int u = 0; u < 4; u++) { ax[u] = 0.f; ay[u] = 0.f; az[u] = 0.f; aw[u] = 0.f; }
        if (grp == 0) {  // self row: h = agg + x (enters via cross-group reduce)
            uint2 v = *(const uint2*)(xwb + ((size_t)node << 7) + l16 * 8);
            ax[0] += __int_as_float((int)(v.x << 16));
            ay[0] += __int_as_float((int)(v.x & 0xffff0000u));
            az[0] += __int_as_float((int)(v.y << 16));
            aw[0] += __int_as_float((int)(v.y & 0xffff0000u));
        }
        int base = rb, rem = re - rb;
        while (rem > 0) {
            int take = min(rem, 64);
            int nb = adj[base + min(lane, take - 1)];  // byte offsets
            int j = 0;
            for (; j + 16 <= take; j += 16) {
                #pragma unroll
                for (int u = 0; u < 4; u++) {
                    int o = __shfl(nb, j + u * 4 + grp);
                    uint2 v = *(const uint2*)(xwb + o + l16 * 8);
                    ax[u] += __int_as_float((int)(v.x << 16));
                    ay[u] += __int_as_float((int)(v.x & 0xffff0000u));
                    az[u] += __int_as_float((int)(v.y << 16));
                    aw[u] += __int_as_float((int)(v.y & 0xffff0000u));
                }
            }
            for (; j < take; j += 4) {
                int e = j + grp;
                int o = __shfl(nb, min(e, take - 1));
                if (e < take) {
                    uint2 v = *(const uint2*)(xwb + o + l16 * 8);
                    ax[0] += __int_as_float((int)(v.x << 16));
                    ay[0] += __int_as_float((int)(v.x & 0xffff0000u));
                    az[0] += __int_as_float((int)(v.y << 16));
                    aw[0] += __int_as_float((int)(v.y & 0xffff0000u));
                }
            }
            base += take; rem -= take;
        }
        float X = (ax[0] + ax[1]) + (ax[2] + ax[3]);
        float Y = (ay[0] + ay[1]) + (ay[2] + ay[3]);
        float Z = (az[0] + az[1]) + (az[2] + az[3]);
        float W = (aw[0] + aw[1]) + (aw[2] + aw[3]);
        X += __shfl_xor(X, 16); X += __shfl_xor(X, 32);
        Y += __shfl_xor(Y, 16); Y += __shfl_xor(Y, 32);
        Z += __shfl_xor(Z, 16); Z += __shfl_xor(Z, 32);
        W += __shfl_xor(W, 16); W += __shfl_xor(W, 32);
        // lane s holds channels 4*(s&15)+{0..3} in X..W (replicated across groups).
        // Build A-frag (row-0 broadcast to all 16 m-rows): a0 = k 0..31, a1 = k 32..63.
        // channel c = grp*8+j -> src lane grp*2 + (j>>2), comp j&3.
        bf16x8 a0, a1;
        {
            int s0 = grp * 2, s1 = grp * 2 + 1;
            a0[0] = f2bf(__shfl(X, s0)); a0[1] = f2bf(__shfl(Y, s0));
            a0[2] = f2bf(__shfl(Z, s0)); a0[3] = f2bf(__shfl(W, s0));
            a0[4] = f2bf(__shfl(X, s1)); a0[5] = f2bf(__shfl(Y, s1));
            a0[6] = f2bf(__shfl(Z, s1)); a0[7] = f2bf(__shfl(W, s1));
            int s2 = 8 + grp * 2, s3 = 8 + grp * 2 + 1;
            a1[0] = f2bf(__shfl(X, s2)); a1[1] = f2bf(__shfl(Y, s2));
            a1[2] = f2bf(__shfl(Z, s2)); a1[3] = f2bf(__shfl(W, s2));
            a1[4] = f2bf(__shfl(X, s3)); a1[5] = f2bf(__shfl(Y, s3));
            a1[6] = f2bf(__shfl(Z, s3)); a1[7] = f2bf(__shfl(W, s3));
        }
        #pragma unroll
        for (int colt = 0; colt < 4; colt++) {
            f32x4 acc = {0.f, 0.f, 0.f, 0.f};
            acc = __builtin_amdgcn_mfma_f32_16x16x32_bf16(a0, wb[colt * 2 + 0], acc, 0, 0, 0);
            acc = __builtin_amdgcn_mfma_f32_16x16x32_bf16(a1, wb[colt * 2 + 1], acc, 0, 0, 0);
            if (grp == 0) {  // all D rows identical; take row 0 from lanes 0-15
                float s = acc[0] + bcol[colt];
                short hb = f2bf(s);
                h1buf[(size_t)idx * 64 + colt * 16 + l16] = *(__hip_bfloat16*)&hb;
                float st = bf2f(hb);
                sS[colt] += st;
                sQ[colt] += st * st;
            }
        }
    }
    // BN partials: per-wave stats live on lanes 0-15 (grp 0)
    if (grp == 0) {
        #pragma unroll
        for (int colt = 0; colt < 4; colt++) {
            lds_red[wave][colt * 16 + l16] = sS[colt];
            lds_red[wave][64 + colt * 16 + l16] = sQ[colt];
        }
    }
    __syncthreads();
    if (threadIdx.x < 128) {
        float v = lds_red[0][threadIdx.x] + lds_red[1][threadIdx.x] +
                  lds_red[2][threadIdx.x] + lds_red[3][threadIdx.x];
        atomicAdd(&bnacc[(blockIdx.x & (NSHADOW - 1)) * 128 + threadIdx.x], v);
    }
    // -------- fused pool of previous layer (reads same xw state) --------
    if (tpool >= 0) {
        int lo = wid * 64;
        if (lo < NN) {
            int hi = min(lo + 64, NN);
            float acc = 0.f;
            int curg = batch[lo];
            for (int n = lo; n < hi; n++) {
                int g = batch[n];
                if (g != curg) {
                    atomicAdd(&z[curg * (HH * LL) + tpool * HH + lane], acc);
                    acc = 0.f;
                    curg = g;
                }
                acc += __bfloat162float(xw[(size_t)n * 64 + lane]);
            }
            atomicAdd(&z[curg * (HH * LL) + tpool * HH + lane], acc);
        }
    }
}

// ---------------- MFMA C: xw[node] = relu(bn(h1)) @ W2 + b2 ----------------
__global__ __launch_bounds__(256) void k_cmfma(
    __hip_bfloat16* __restrict__ xw, const int* __restrict__ clist_c,
    const int* __restrict__ ccount_c, const float* __restrict__ g1c,
    const float* __restrict__ be1c, const short* __restrict__ wf2,
    const float* __restrict__ b2c, const __hip_bfloat16* __restrict__ h1buf,
    const float* __restrict__ bnacc) {
    __shared__ float lds_scale[64];
    __shared__ float lds_shift[64];
    int cnt = *ccount_c;
    int tiles = (cnt + 15) >> 4;
    int lane = threadIdx.x & 63;
    int wave = threadIdx.x >> 6;
    int wid = blockIdx.x * 4 + wave;
    int nwaves = gridDim.x * 4;
    int quad = lane >> 4;
    int l15 = lane & 15;

    if (threadIdx.x < 64) {
        float s = 0.f, q = 0.f;
        #pragma unroll
        for (int sh = 0; sh < NSHADOW; sh++) {
            s += bnacc[sh * 128 + threadIdx.x];
            q += bnacc[sh * 128 + 64 + threadIdx.x];
        }
        float fc = fmaxf((float)cnt, 1.f);
        float mean = s / fc;
        float var = q / fc - mean * mean;
        float sc = g1c[threadIdx.x] * rsqrtf(var + BN_EPS);
        lds_scale[threadIdx.x] = sc;
        lds_shift[threadIdx.x] = be1c[threadIdx.x] - mean * sc;
    }
    __syncthreads();

    bf16x8 wb[8];
    #pragma unroll
    for (int f = 0; f < 8; f++)
        wb[f] = *(const bf16x8*)(wf2 + f * 512 + lane * 8);
    float bcol[4];
    #pragma unroll
    for (int colt = 0; colt < 4; colt++) bcol[colt] = b2c[colt * 16 + l15];
    float scl0[8], sft0[8], scl1[8], sft1[8];
    #pragma unroll
    for (int j = 0; j < 8; j++) {
        int ch = quad * 8 + j;
        scl0[j] = lds_scale[ch];      sft0[j] = lds_shift[ch];
        scl1[j] = lds_scale[ch + 32]; sft1[j] = lds_shift[ch + 32];
    }

    for (int tile = wid; tile < tiles; tile += nwaves) {
        int tb = tile << 4;
        int row = tb + l15;
        const __hip_bfloat16* hr = h1buf + (size_t)row * 64 + quad * 8;
        bf16x8 h0 = *(const bf16x8*)hr;
        bf16x8 h1f = *(const bf16x8*)(hr + 32);
        bf16x8 a0, a1;
        #pragma unroll
        for (int j = 0; j < 8; j++) {
            a0[j] = f2bf(fmaxf(bf2f(h0[j]) * scl0[j] + sft0[j], 0.f));
            a1[j] = f2bf(fmaxf(bf2f(h1f[j]) * scl1[j] + sft1[j], 0.f));
        }
        #pragma unroll
        for (int colt = 0; colt < 4; colt++) {
            f32x4 acc = {0.f, 0.f, 0.f, 0.f};
            acc = __builtin_amdgcn_mfma_f32_16x16x32_bf16(a0, wb[colt * 2 + 0], acc, 0, 0, 0);
            acc = __builtin_amdgcn_mfma_f32_16x16x32_bf16(a1, wb[colt * 2 + 1], acc, 0, 0, 0);
            #pragma unroll
            for (int r = 0; r < 4; r++) {
                int nrow = tb + quad * 4 + r;
                if (nrow < cnt) {
                    int node = clist_c[nrow];
                    xw[(size_t)node * 64 + colt * 16 + l15] =
                        __float2bfloat16(acc[r] + bcol[colt]);
                }
            }
        }
    }
}

// ---------------- pooling (standalone, used for last layer) ----------------
__global__ void k_pool(const __hip_bfloat16* __restrict__ xw, const int* __restrict__ batch,
                       float* __restrict__ z, int t) {
    const int CHUNK = 64;
    int lane = threadIdx.x & 63;
    int wg = (blockIdx.x * blockDim.x + threadIdx.x) >> 6;
    int lo = wg * CHUNK;
    if (lo >= NN) return;
    int hi = min(lo + CHUNK, NN);
    float acc = 0.f;
    int curg = batch[lo];
    for (int n = lo; n < hi; n++) {
        int g = batch[n];
        if (g != curg) {
            atomicAdd(&z[curg * (HH * LL) + t * HH + lane], acc);
            acc = 0.f;
            curg = g;
        }
        acc += __bfloat162float(xw[(size_t)n * 64 + lane]);
    }
    atomicAdd(&z[curg * (HH * LL) + t * HH + lane], acc);
}

// ---------------- final MLP (split for parallelism, R7-proven) ----------------
__global__ __launch_bounds__(256) void k_final1(
    const float* __restrict__ z, const float* __restrict__ Wp1,
    const float* __restrict__ bp1, float* __restrict__ hbuf) {
    __shared__ float red[256];
    int g = blockIdx.x;
    int k = threadIdx.x & 63;
    int part = threadIdx.x >> 6;  // 4 parts x 48 j's
    float s = 0.f;
    #pragma unroll 8
    for (int j = part * 48; j < (part + 1) * 48; j++)
        s += z[g * (HH * LL) + j] * Wp1[j * 64 + k];
    red[threadIdx.x] = s;
    __syncthreads();
    if (part == 0)
        hbuf[g * 64 + k] = red[k] + red[64 + k] + red[128 + k] + red[192 + k] + bp1[k];
}

__global__ __launch_bounds__(256) void k_final2(
    const float* __restrict__ hbuf, const float* __restrict__ gp,
    const float* __restrict__ bep, const float* __restrict__ Wp2,
    const float* __restrict__ bp2, float* __restrict__ out) {
    __shared__ float lds[64 * 64];
    __shared__ float sscale[64];
    __shared__ float sshift[64];
    int tid = threadIdx.x;
    for (int i = tid; i < 64 * 64; i += 256) lds[i] = hbuf[i];
    __syncthreads();
    if (tid < 64) {
        float s = 0.f, q = 0.f;
        for (int g = 0; g < 64; g++) { float v = lds[g * 64 + tid]; s += v; q += v * v; }
        float mean = s / 64.f;
        float var = q / 64.f - mean * mean;
        float sc = gp[tid] * rsqrtf(var + BN_EPS);
        sscale[tid] = sc;
        sshift[tid] = bep[tid] - mean * sc;
    }
    __syncthreads();
    for (int i = tid; i < 64 * 64; i += 256) {
        int k = i & 63;
        lds[i] = fmaxf(lds[i] * sscale[k] + sshift[k], 0.f);
    }
    __syncthreads();
    for (int i = tid; i < 64 * 64; i += 256) {
        int g = i >> 6, o = i & 63;
        float s = bp2[o];
        #pragma unroll 8
        for (int k = 0; k < 64; k++) s += lds[g * 64 + k] * Wp2[k * 64 + o];
        out[g * 64 + o] = s;
    }
}

// ---------------- launch ----------------
extern "C" void kernel_launch(void* const* d_in, const int* in_sizes, int n_in,
                              void* d_out, int out_size, void* d_ws, size_t ws_size,
                              hipStream_t stream) {
    const float* x_in = (const float*)d_in[0];
    const int* labels = (const int*)d_in[1];
    const int* esrc = (const int*)d_in[2];
    const int* edst = esrc + EE;
    const int* batch = (const int*)d_in[3];
    const float* W1 = (const float*)d_in[4];
    const float* b1 = (const float*)d_in[5];
    const float* g1 = (const float*)d_in[6];
    const float* be1 = (const float*)d_in[7];
    const float* W2 = (const float*)d_in[8];
    const float* b2 = (const float*)d_in[9];
    const float* Wp1 = (const float*)d_in[10];
    const float* bp1 = (const float*)d_in[11];
    const float* gp = (const float*)d_in[12];
    const float* bep = (const float*)d_in[13];
    const float* Wp2 = (const float*)d_in[14];
    const float* bp2 = (const float*)d_in[15];
    float* out = (float*)d_out;

    char* p = (char*)d_ws;
    auto carve = [&](size_t bytes) -> void* {
        void* r = (void*)p;
        p += (bytes + 255) & ~(size_t)255;
        return r;
    };
    // ---- zeroed region (one memset) ----
    float* bnacc = (float*)carve((size_t)LL * CC * NSHADOW * 128 * 4);
    float* z     = (float*)carve((size_t)GG * HH * LL * 4);
    int*   deg   = (int*)carve((size_t)NN * 4);
    size_t zero_bytes = (size_t)(p - (char*)d_ws);
    // ---- rest ----
    int*   ccount  = (int*)carve(CC * 4);
    int*   blockcnt= (int*)carve((size_t)CC * SBLK * 4);
    int*   coffs   = (int*)carve((size_t)CC * SBLK * 4);
    int*   dpart   = (int*)carve((size_t)SBLK * 4);
    int*   dbase   = (int*)carve((size_t)SBLK * 4);
    __hip_bfloat16* xw    = (__hip_bfloat16*)carve((size_t)NN * 64 * 2);
    __hip_bfloat16* h1buf = (__hip_bfloat16*)carve((size_t)NN * 64 * 2);
    short* wf      = (short*)carve((size_t)24 * 4096 * 2);
    float* hbuf    = (float*)carve((size_t)GG * 64 * 4);
    int*   rowptr  = (int*)carve((size_t)(NN + 1) * 4);
    int*   cursor  = (int*)carve((size_t)NN * 4);
    int*   adj     = (int*)carve((size_t)EE * 4);
    int*   clist   = (int*)carve((size_t)CC * NN * 4);

    hipMemsetAsync(d_ws, 0, zero_bytes, stream);

    k_deghist<<<ECHUNKS, 256, 0, stream>>>(edst, deg, labels, blockcnt, x_in, xw, W1, W2, wf);
    k_scancombo<<<SBLK + 1, 256, 0, stream>>>(deg, rowptr, dpart, blockcnt, coffs, ccount);
    k_dscan2<<<1, 256, 0, stream>>>(dpart, dbase, rowptr);
    k_cfill_dscan3<<<SBLK, 256, 0, stream>>>(rowptr, dbase, cursor, labels, coffs, clist);
    k_fill<<<ECHUNKS * 8, 256, 0, stream>>>(esrc, edst, cursor, adj);

    for (int t = 0; t < LL; t++) {
        for (int c = 0; c < CC; c++) {
            int tc = t * CC + c;
            int tpool = (c == 0) ? (t - 1) : -1;  // fuse previous layer's pool into gather
            k_gl1<<<GIN_BLOCKS, 256, 0, stream>>>(
                xw, adj, rowptr, clist + c * NN, ccount + c,
                wf + (size_t)tc * 4096, b1 + (size_t)tc * 64, h1buf,
                bnacc + (size_t)tc * NSHADOW * 128, batch, z, tpool);
            k_cmfma<<<MM_BLOCKS, 256, 0, stream>>>(
                xw, clist + c * NN, ccount + c,
                g1 + (size_t)tc * 64, be1 + (size_t)tc * 64,
                wf + (size_t)(12 + tc) * 4096, b2 + (size_t)tc * 64,
                h1buf, bnacc + (size_t)tc * NSHADOW * 128);
        }
    }
    // last layer's pool (standalone)
    {
        int pool_waves = (NN + 63) / 64;
        int pool_blocks = (pool_waves * 64 + 255) / 256;
        k_pool<<<pool_blocks, 256, 0, stream>>>(xw, batch, z, LL - 1);
    }
    k_final1<<<GG, 256, 0, stream>>>(z, Wp1, bp1, hbuf);
    k_final2<<<1, 256, 0, stream>>>(hbuf, gp, bep, Wp2, bp2, out);
}

// Round 18
// 553.520 us; speedup vs baseline: 1.0863x; 1.0863x over previous
//
#include <hip/hip_runtime.h>
#include <hip/hip_bf16.h>

#define NN 50000
#define EE 800000
#define GG 64
#define LL 3
#define CC 4
#define HH 64
#define BN_EPS 1e-5f
#define NSHADOW 4
#define SBLK 196          // ceil(NN/256) node-parallel blocks
#define GIN_BLOCKS 2048   // grid-stride gather kernels (8192 waves)
#define MM_BLOCKS 256     // MFMA GEMM kernels (1024 waves >= 782 tiles)
#define ECHUNKS 3125      // ceil(EE/256)
#define NODE_RANGE 6250   // NN/8, dst-range binning for k_fill

// NOTE: harness passes ALL integer inputs as int32 (edge_index/batch included).
// NOTE: cooperative launch + grid.sync 4x SLOWER than kernel barriers (R5).
// NOTE: single-block k_final 90us latency-bound -> final MLP split (R7).
// NOTE: multi-node-per-wave gather serializes latency chains (R7/R12); tile-barrier
//       gather+lin1 fusion couples waves to slowest node (R15: +9us); per-wave
//       MFMA lin1 fusion costs 64 shfl+cvt/node at 1/16 MFMA utilization
//       (R17: +45us) — gather stays 1 node/wave, SEPARATE k_lin1 (amortizes
//       MFMA over 16 real rows). This is the measured-best structure (R16: 556us).
// NOTE: R11: GIN kernels are VALU-ISSUE bound; readlane broadcasts 745->646us.
// NOTE: R13: MLPs on MFMA 16x16x32 bf16: 654->563us.
//       Fragment layouts: A[m=lane&15][k=quad*8+j]; C/D[col=lane&15][row=quad*4+reg].
// NOTE: R14: range-major binned k_fill 51->46us — floor for atomic scatter fill.
// NOTE: R16: 4-row vectorized gather neutral vs R14 -> gather is at a scattered-row
//       latency/fabric floor (~1.5TB/s effective); parallelism does not move it.
//       fp8 rows inadmissible (projected absmax ~0.25 > 0.065 threshold).

typedef __attribute__((ext_vector_type(8))) short bf16x8;
typedef __attribute__((ext_vector_type(4))) float f32x4;

__device__ __forceinline__ float bf2f(short s) {
    return __int_as_float(((int)(unsigned short)s) << 16);
}
__device__ __forceinline__ short f2bf(float v) {
    __hip_bfloat16 hb = __float2bfloat16(v);
    return *(short*)&hb;
}

// ---------------- setup kernels ----------------

// fused: x fp32->bf16 convert + degree count + cluster histogram + W-fragment pack.
__global__ void k_deghist(const int* __restrict__ dst, int* __restrict__ deg,
                          const int* __restrict__ labels, int* __restrict__ blockcnt,
                          const float* __restrict__ x_in, __hip_bfloat16* __restrict__ xw,
                          const float* __restrict__ W1, const float* __restrict__ W2,
                          short* __restrict__ wf) {
    __shared__ int cnt[CC];
    int tid = threadIdx.x;
    for (int i = blockIdx.x * 256 + tid; i < NN * 64; i += gridDim.x * 256)
        xw[i] = __float2bfloat16(x_in[i]);
    // W pack: first 384 blocks, one element per thread (24*4096 = 98304)
    int o = blockIdx.x * 256 + tid;
    if (o < 24 * 4096) {
        int m = o >> 12;
        int r = o & 4095;
        int colt = r >> 10;
        int fragk = (r >> 9) & 1;
        int lane = (r >> 3) & 63;
        int j = r & 7;
        int k = fragk * 32 + ((lane >> 4) << 3) + j;
        int n = colt * 16 + (lane & 15);
        const float* src = (m < 12) ? (W1 + (size_t)m * 4096) : (W2 + (size_t)(m - 12) * 4096);
        wf[o] = f2bf(src[k * 64 + n]);
    }
    bool hist = (blockIdx.x < SBLK);
    if (hist && tid < CC) cnt[tid] = 0;
    __syncthreads();
    int gid = blockIdx.x * 256 + tid;
    if (gid < EE) atomicAdd(&deg[dst[gid]], 1);
    if (hist && gid < NN) atomicAdd(&cnt[labels[gid]], 1);
    __syncthreads();
    if (hist && tid < CC) blockcnt[tid * SBLK + blockIdx.x] = cnt[tid];
}

__global__ __launch_bounds__(256) void k_scancombo(
    const int* __restrict__ deg, int* __restrict__ rowptr, int* __restrict__ dpart,
    const int* __restrict__ blockcnt, int* __restrict__ coffs, int* __restrict__ ccount) {
    __shared__ int smem[CC * 256];
    int tid = threadIdx.x;
    if (blockIdx.x < SBLK) {
        int i = blockIdx.x * 256 + tid;
        int v = (i < NN) ? deg[i] : 0;
        smem[tid] = v;
        __syncthreads();
        for (int off = 1; off < 256; off <<= 1) {
            int u = (tid >= off) ? smem[tid - off] : 0;
            __syncthreads();
            smem[tid] += u;
            __syncthreads();
        }
        if (i < NN) rowptr[i] = smem[tid] - v;  // local exclusive
        if (tid == 255) dpart[blockIdx.x] = smem[255];
    } else {
        int own[CC];
        for (int c = 0; c < CC; c++) {
            own[c] = (tid < SBLK) ? blockcnt[c * SBLK + tid] : 0;
            smem[c * 256 + tid] = own[c];
        }
        __syncthreads();
        for (int off = 1; off < 256; off <<= 1) {
            int v[CC];
            for (int c = 0; c < CC; c++) v[c] = (tid >= off) ? smem[c * 256 + tid - off] : 0;
            __syncthreads();
            for (int c = 0; c < CC; c++) smem[c * 256 + tid] += v[c];
            __syncthreads();
        }
        if (tid < SBLK)
            for (int c = 0; c < CC; c++) coffs[c * SBLK + tid] = smem[c * 256 + tid] - own[c];
        if (tid == 0)
            for (int c = 0; c < CC; c++) ccount[c] = smem[c * 256 + 255];
    }
}

__global__ __launch_bounds__(256) void k_dscan2(int* __restrict__ dpart,
                                                int* __restrict__ dbase,
                                                int* __restrict__ rowptr) {
    __shared__ int s[256];
    int tid = threadIdx.x;
    int v = (tid < SBLK) ? dpart[tid] : 0;
    s[tid] = v;
    __syncthreads();
    for (int off = 1; off < 256; off <<= 1) {
        int u = (tid >= off) ? s[tid - off] : 0;
        __syncthreads();
        s[tid] += u;
        __syncthreads();
    }
    if (tid < SBLK) dbase[tid] = s[tid] - v;
    if (tid == 0) rowptr[NN] = EE;
}

__global__ __launch_bounds__(256) void k_cfill_dscan3(
    int* __restrict__ rowptr, const int* __restrict__ dbase, int* __restrict__ cursor,
    const int* __restrict__ labels, const int* __restrict__ coffs, int* __restrict__ clist) {
    __shared__ int pos[CC];
    int tid = threadIdx.x;
    if (tid < CC) pos[tid] = coffs[tid * SBLK + blockIdx.x];
    __syncthreads();
    int i = blockIdx.x * 256 + tid;
    if (i < NN) {
        int r = rowptr[i] + dbase[blockIdx.x];
        rowptr[i] = r;
        cursor[i] = r;
        int c = labels[i];
        int p = atomicAdd(&pos[c], 1);
        clist[c * NN + p] = i;
    }
}

// RANGE-MAJOR binned CSR fill (R14). adj stores BYTE offsets: src<<7.
__global__ void k_fill(const int* __restrict__ src, const int* __restrict__ dst,
                       int* __restrict__ cursor, int* __restrict__ adj) {
    int range = blockIdx.x / ECHUNKS;
    int e = (blockIdx.x - range * ECHUNKS) * 256 + threadIdx.x;
    if (e < EE) {
        int d = dst[e];
        int lo = range * NODE_RANGE;
        if (d >= lo && d < lo + NODE_RANGE) {
            int pos = atomicAdd(&cursor[d], 1);
            adj[pos] = src[e] << 7;
        }
    }
}

// ---------------- gather kernel (1 node/wave, 4 rows/issue, 8 chains) ----------------
// Lanes split into 4 groups of 16; each group loads a different neighbor row
// (16 lanes x 8B = 128B). Cross-group shfl_xor reduce at the end; group 0 writes.
// agg[idx] = x[node] + sum_{j->node} x[j]  (bf16 out).
// Optional fused pool of previous layer (tpool >= 0).
__global__ __launch_bounds__(256) void k_gather(
    const __hip_bfloat16* __restrict__ xw, const int* __restrict__ adj,
    const int* __restrict__ rowptr, const int* __restrict__ clist_c,
    const int* __restrict__ ccount_c, __hip_bfloat16* __restrict__ aggbuf,
    const int* __restrict__ batch, float* __restrict__ z, int tpool) {
    int cnt = *ccount_c;
    int lane = threadIdx.x & 63;
    int wave = threadIdx.x >> 6;
    int wid = blockIdx.x * 4 + wave;
    int nwaves = gridDim.x * 4;
    int grp = lane >> 4;   // 0..3: which row of the 4-row issue group
    int l16 = lane & 15;   // position within the 16-lane row loader
    const char* xwb = (const char*)xw;
    int idx = wid;
    int node_next = (idx < cnt) ? clist_c[idx] : 0;
    for (; idx < cnt; idx += nwaves) {
        int node = node_next;
        int nidx = idx + nwaves;
        if (nidx < cnt) node_next = clist_c[nidx];  // prefetch next node id
        int rb = rowptr[node], re = rowptr[node + 1];
        float ax[8], ay[8], az[8], aw[8];
        #pragma unroll
        for (int u = 0; u < 8; u++) { ax[u] = 0.f; ay[u] = 0.f; az[u] = 0.f; aw[u] = 0.f; }
        if (grp == 0) {  // self row: h = agg + x (summed in via cross-group reduce)
            uint2 v = *(const uint2*)(xwb + ((size_t)node << 7) + l16 * 8);
            ax[0] += __int_as_float((int)(v.x << 16));
            ay[0] += __int_as_float((int)(v.x & 0xffff0000u));
            az[0] += __int_as_float((int)(v.y << 16));
            aw[0] += __int_as_float((int)(v.y & 0xffff0000u));
        }
        int base = rb, rem = re - rb;
        while (rem > 0) {
            int take = min(rem, 64);
            int nb = adj[base + min(lane, take - 1)];  // byte offsets
            int j = 0;
            for (; j + 32 <= take; j += 32) {
                #pragma unroll
                for (int u = 0; u < 8; u++) {
                    int o = __shfl(nb, j + u * 4 + grp);
                    uint2 v = *(const uint2*)(xwb + o + l16 * 8);
                    ax[u] += __int_as_float((int)(v.x << 16));
                    ay[u] += __int_as_float((int)(v.x & 0xffff0000u));
                    az[u] += __int_as_float((int)(v.y << 16));
                    aw[u] += __int_as_float((int)(v.y & 0xffff0000u));
                }
            }
            for (; j + 16 <= take; j += 16) {
                #pragma unroll
                for (int u = 0; u < 4; u++) {
                    int o = __shfl(nb, j + u * 4 + grp);
                    uint2 v = *(const uint2*)(xwb + o + l16 * 8);
                    ax[u] += __int_as_float((int)(v.x << 16));
                    ay[u] += __int_as_float((int)(v.x & 0xffff0000u));
                    az[u] += __int_as_float((int)(v.y << 16));
                    aw[u] += __int_as_float((int)(v.y & 0xffff0000u));
                }
            }
            for (; j < take; j += 4) {
                int e = j + grp;
                int o = __shfl(nb, min(e, take - 1));
                if (e < take) {
                    uint2 v = *(const uint2*)(xwb + o + l16 * 8);
                    ax[0] += __int_as_float((int)(v.x << 16));
                    ay[0] += __int_as_float((int)(v.x & 0xffff0000u));
                    az[0] += __int_as_float((int)(v.y << 16));
                    aw[0] += __int_as_float((int)(v.y & 0xffff0000u));
                }
            }
            base += take; rem -= take;
        }
        float X = ((ax[0] + ax[1]) + (ax[2] + ax[3])) + ((ax[4] + ax[5]) + (ax[6] + ax[7]));
        float Y = ((ay[0] + ay[1]) + (ay[2] + ay[3])) + ((ay[4] + ay[5]) + (ay[6] + ay[7]));
        float Z = ((az[0] + az[1]) + (az[2] + az[3])) + ((az[4] + az[5]) + (az[6] + az[7]));
        float W = ((aw[0] + aw[1]) + (aw[2] + aw[3])) + ((aw[4] + aw[5]) + (aw[6] + aw[7]));
        X += __shfl_xor(X, 16); X += __shfl_xor(X, 32);
        Y += __shfl_xor(Y, 16); Y += __shfl_xor(Y, 32);
        Z += __shfl_xor(Z, 16); Z += __shfl_xor(Z, 32);
        W += __shfl_xor(W, 16); W += __shfl_xor(W, 32);
        if (grp == 0) {
            ushort4 st;
            st.x = (unsigned short)f2bf(X);
            st.y = (unsigned short)f2bf(Y);
            st.z = (unsigned short)f2bf(Z);
            st.w = (unsigned short)f2bf(W);
            *(ushort4*)((char*)aggbuf + ((size_t)idx << 7) + l16 * 8) = st;
        }
    }
    // -------- fused pool of previous layer (reads same xw state) --------
    if (tpool >= 0) {
        int lo = wid * 64;
        if (lo < NN) {
            int hi = min(lo + 64, NN);
            float acc = 0.f;
            int curg = batch[lo];
            for (int n = lo; n < hi; n++) {
                int g = batch[n];
                if (g != curg) {
                    atomicAdd(&z[curg * (HH * LL) + tpool * HH + lane], acc);
                    acc = 0.f;
                    curg = g;
                }
                acc += __bfloat162float(xw[(size_t)n * 64 + lane]);
            }
            atomicAdd(&z[curg * (HH * LL) + tpool * HH + lane], acc);
        }
    }
}

// ---------------- MFMA Lin1: h1 = agg @ W1 + b1 ; BN partials ----------------
__global__ __launch_bounds__(256) void k_lin1(
    const __hip_bfloat16* __restrict__ aggbuf, const int* __restrict__ ccount_c,
    const short* __restrict__ wf1, const float* __restrict__ b1c,
    __hip_bfloat16* __restrict__ h1buf, float* __restrict__ bnacc) {
    int cnt = *ccount_c;
    int tiles = (cnt + 15) >> 4;
    int lane = threadIdx.x & 63;
    int wave = threadIdx.x >> 6;
    int wid = blockIdx.x * 4 + wave;
    int nwaves = gridDim.x * 4;
    int quad = lane >> 4;
    int l15 = lane & 15;

    bf16x8 wb[8];
    #pragma unroll
    for (int f = 0; f < 8; f++)
        wb[f] = *(const bf16x8*)(wf1 + f * 512 + lane * 8);
    float bcol[4];
    #pragma unroll
    for (int colt = 0; colt < 4; colt++) bcol[colt] = b1c[colt * 16 + l15];

    float sS[4] = {0.f, 0.f, 0.f, 0.f};
    float sQ[4] = {0.f, 0.f, 0.f, 0.f};

    for (int tile = wid; tile < tiles; tile += nwaves) {
        int tb = tile << 4;
        int row = tb + l15;
        const __hip_bfloat16* ar = aggbuf + (size_t)row * 64 + quad * 8;
        bf16x8 a0 = *(const bf16x8*)ar;
        bf16x8 a1 = *(const bf16x8*)(ar + 32);
        #pragma unroll
        for (int colt = 0; colt < 4; colt++) {
            f32x4 acc = {0.f, 0.f, 0.f, 0.f};
            acc = __builtin_amdgcn_mfma_f32_16x16x32_bf16(a0, wb[colt * 2 + 0], acc, 0, 0, 0);
            acc = __builtin_amdgcn_mfma_f32_16x16x32_bf16(a1, wb[colt * 2 + 1], acc, 0, 0, 0);
            #pragma unroll
            for (int r = 0; r < 4; r++) {
                int nrow = tb + quad * 4 + r;
                if (nrow < cnt) {
                    float s = acc[r] + bcol[colt];
                    __hip_bfloat16 hb = __float2bfloat16(s);
                    h1buf[(size_t)nrow * 64 + colt * 16 + l15] = hb;
                    float st = __bfloat162float(hb);
                    sS[colt] += st;
                    sQ[colt] += st * st;
                }
            }
        }
    }
    // reduce across quads (cols replicated in lanes l15, +16, +32, +48)
    #pragma unroll
    for (int colt = 0; colt < 4; colt++) {
        sS[colt] += __shfl_xor(sS[colt], 16); sS[colt] += __shfl_xor(sS[colt], 32);
        sQ[colt] += __shfl_xor(sQ[colt], 16); sQ[colt] += __shfl_xor(sQ[colt], 32);
    }
    if (quad == 0) {
        int slot = (blockIdx.x & (NSHADOW - 1)) * 128;
        #pragma unroll
        for (int colt = 0; colt < 4; colt++) {
            atomicAdd(&bnacc[slot + colt * 16 + l15], sS[colt]);
            atomicAdd(&bnacc[slot + 64 + colt * 16 + l15], sQ[colt]);
        }
    }
}

// ---------------- MFMA C: xw[node] = relu(bn(h1)) @ W2 + b2 ----------------
__global__ __launch_bounds__(256) void k_cmfma(
    __hip_bfloat16* __restrict__ xw, const int* __restrict__ clist_c,
    const int* __restrict__ ccount_c, const float* __restrict__ g1c,
    const float* __restrict__ be1c, const short* __restrict__ wf2,
    const float* __restrict__ b2c, const __hip_bfloat16* __restrict__ h1buf,
    const float* __restrict__ bnacc) {
    __shared__ float lds_scale[64];
    __shared__ float lds_shift[64];
    int cnt = *ccount_c;
    int tiles = (cnt + 15) >> 4;
    int lane = threadIdx.x & 63;
    int wave = threadIdx.x >> 6;
    int wid = blockIdx.x * 4 + wave;
    int nwaves = gridDim.x * 4;
    int quad = lane >> 4;
    int l15 = lane & 15;

    if (threadIdx.x < 64) {
        float s = 0.f, q = 0.f;
        #pragma unroll
        for (int sh = 0; sh < NSHADOW; sh++) {
            s += bnacc[sh * 128 + threadIdx.x];
            q += bnacc[sh * 128 + 64 + threadIdx.x];
        }
        float fc = fmaxf((float)cnt, 1.f);
        float mean = s / fc;
        float var = q / fc - mean * mean;
        float sc = g1c[threadIdx.x] * rsqrtf(var + BN_EPS);
        lds_scale[threadIdx.x] = sc;
        lds_shift[threadIdx.x] = be1c[threadIdx.x] - mean * sc;
    }
    __syncthreads();

    bf16x8 wb[8];
    #pragma unroll
    for (int f = 0; f < 8; f++)
        wb[f] = *(const bf16x8*)(wf2 + f * 512 + lane * 8);
    float bcol[4];
    #pragma unroll
    for (int colt = 0; colt < 4; colt++) bcol[colt] = b2c[colt * 16 + l15];
    float scl0[8], sft0[8], scl1[8], sft1[8];
    #pragma unroll
    for (int j = 0; j < 8; j++) {
        int ch = quad * 8 + j;
        scl0[j] = lds_scale[ch];      sft0[j] = lds_shift[ch];
        scl1[j] = lds_scale[ch + 32]; sft1[j] = lds_shift[ch + 32];
    }

    for (int tile = wid; tile < tiles; tile += nwaves) {
        int tb = tile << 4;
        int row = tb + l15;
        const __hip_bfloat16* hr = h1buf + (size_t)row * 64 + quad * 8;
        bf16x8 h0 = *(const bf16x8*)hr;
        bf16x8 h1f = *(const bf16x8*)(hr + 32);
        bf16x8 a0, a1;
        #pragma unroll
        for (int j = 0; j < 8; j++) {
            a0[j] = f2bf(fmaxf(bf2f(h0[j]) * scl0[j] + sft0[j], 0.f));
            a1[j] = f2bf(fmaxf(bf2f(h1f[j]) * scl1[j] + sft1[j], 0.f));
        }
        #pragma unroll
        for (int colt = 0; colt < 4; colt++) {
            f32x4 acc = {0.f, 0.f, 0.f, 0.f};
            acc = __builtin_amdgcn_mfma_f32_16x16x32_bf16(a0, wb[colt * 2 + 0], acc, 0, 0, 0);
            acc = __builtin_amdgcn_mfma_f32_16x16x32_bf16(a1, wb[colt * 2 + 1], acc, 0, 0, 0);
            #pragma unroll
            for (int r = 0; r < 4; r++) {
                int nrow = tb + quad * 4 + r;
                if (nrow < cnt) {
                    int node = clist_c[nrow];
                    xw[(size_t)node * 64 + colt * 16 + l15] =
                        __float2bfloat16(acc[r] + bcol[colt]);
                }
            }
        }
    }
}

// ---------------- pooling (standalone, used for last layer) ----------------
__global__ void k_pool(const __hip_bfloat16* __restrict__ xw, const int* __restrict__ batch,
                       float* __restrict__ z, int t) {
    const int CHUNK = 64;
    int lane = threadIdx.x & 63;
    int wg = (blockIdx.x * blockDim.x + threadIdx.x) >> 6;
    int lo = wg * CHUNK;
    if (lo >= NN) return;
    int hi = min(lo + CHUNK, NN);
    float acc = 0.f;
    int curg = batch[lo];
    for (int n = lo; n < hi; n++) {
        int g = batch[n];
        if (g != curg) {
            atomicAdd(&z[curg * (HH * LL) + t * HH + lane], acc);
            acc = 0.f;
            curg = g;
        }
        acc += __bfloat162float(xw[(size_t)n * 64 + lane]);
    }
    atomicAdd(&z[curg * (HH * LL) + t * HH + lane], acc);
}

// ---------------- final MLP (split for parallelism, R7-proven) ----------------
__global__ __launch_bounds__(256) void k_final1(
    const float* __restrict__ z, const float* __restrict__ Wp1,
    const float* __restrict__ bp1, float* __restrict__ hbuf) {
    __shared__ float red[256];
    int g = blockIdx.x;
    int k = threadIdx.x & 63;
    int part = threadIdx.x >> 6;  // 4 parts x 48 j's
    float s = 0.f;
    #pragma unroll 8
    for (int j = part * 48; j < (part + 1) * 48; j++)
        s += z[g * (HH * LL) + j] * Wp1[j * 64 + k];
    red[threadIdx.x] = s;
    __syncthreads();
    if (part == 0)
        hbuf[g * 64 + k] = red[k] + red[64 + k] + red[128 + k] + red[192 + k] + bp1[k];
}

__global__ __launch_bounds__(256) void k_final2(
    const float* __restrict__ hbuf, const float* __restrict__ gp,
    const float* __restrict__ bep, const float* __restrict__ Wp2,
    const float* __restrict__ bp2, float* __restrict__ out) {
    __shared__ float lds[64 * 64];
    __shared__ float sscale[64];
    __shared__ float sshift[64];
    int tid = threadIdx.x;
    for (int i = tid; i < 64 * 64; i += 256) lds[i] = hbuf[i];
    __syncthreads();
    if (tid < 64) {
        float s = 0.f, q = 0.f;
        for (int g = 0; g < 64; g++) { float v = lds[g * 64 + tid]; s += v; q += v * v; }
        float mean = s / 64.f;
        float var = q / 64.f - mean * mean;
        float sc = gp[tid] * rsqrtf(var + BN_EPS);
        sscale[tid] = sc;
        sshift[tid] = bep[tid] - mean * sc;
    }
    __syncthreads();
    for (int i = tid; i < 64 * 64; i += 256) {
        int k = i & 63;
        lds[i] = fmaxf(lds[i] * sscale[k] + sshift[k], 0.f);
    }
    __syncthreads();
    for (int i = tid; i < 64 * 64; i += 256) {
        int g = i >> 6, o = i & 63;
        float s = bp2[o];
        #pragma unroll 8
        for (int k = 0; k < 64; k++) s += lds[g * 64 + k] * Wp2[k * 64 + o];
        out[g * 64 + o] = s;
    }
}

// ---------------- launch ----------------
extern "C" void kernel_launch(void* const* d_in, const int* in_sizes, int n_in,
                              void* d_out, int out_size, void* d_ws, size_t ws_size,
                              hipStream_t stream) {
    const float* x_in = (const float*)d_in[0];
    const int* labels = (const int*)d_in[1];
    const int* esrc = (const int*)d_in[2];
    const int* edst = esrc + EE;
    const int* batch = (const int*)d_in[3];
    const float* W1 = (const float*)d_in[4];
    const float* b1 = (const float*)d_in[5];
    const float* g1 = (const float*)d_in[6];
    const float* be1 = (const float*)d_in[7];
    const float* W2 = (const float*)d_in[8];
    const float* b2 = (const float*)d_in[9];
    const float* Wp1 = (const float*)d_in[10];
    const float* bp1 = (const float*)d_in[11];
    const float* gp = (const float*)d_in[12];
    const float* bep = (const float*)d_in[13];
    const float* Wp2 = (const float*)d_in[14];
    const float* bp2 = (const float*)d_in[15];
    float* out = (float*)d_out;

    char* p = (char*)d_ws;
    auto carve = [&](size_t bytes) -> void* {
        void* r = (void*)p;
        p += (bytes + 255) & ~(size_t)255;
        return r;
    };
    // ---- zeroed region (one memset) ----
    float* bnacc = (float*)carve((size_t)LL * CC * NSHADOW * 128 * 4);
    float* z     = (float*)carve((size_t)GG * HH * LL * 4);
    int*   deg   = (int*)carve((size_t)NN * 4);
    size_t zero_bytes = (size_t)(p - (char*)d_ws);
    // ---- rest ----
    int*   ccount  = (int*)carve(CC * 4);
    int*   blockcnt= (int*)carve((size_t)CC * SBLK * 4);
    int*   coffs   = (int*)carve((size_t)CC * SBLK * 4);
    int*   dpart   = (int*)carve((size_t)SBLK * 4);
    int*   dbase   = (int*)carve((size_t)SBLK * 4);
    __hip_bfloat16* xw     = (__hip_bfloat16*)carve((size_t)NN * 64 * 2);
    __hip_bfloat16* aggbuf = (__hip_bfloat16*)carve((size_t)NN * 64 * 2);
    __hip_bfloat16* h1buf  = (__hip_bfloat16*)carve((size_t)NN * 64 * 2);
    short* wf      = (short*)carve((size_t)24 * 4096 * 2);
    float* hbuf    = (float*)carve((size_t)GG * 64 * 4);
    int*   rowptr  = (int*)carve((size_t)(NN + 1) * 4);
    int*   cursor  = (int*)carve((size_t)NN * 4);
    int*   adj     = (int*)carve((size_t)EE * 4);
    int*   clist   = (int*)carve((size_t)CC * NN * 4);

    hipMemsetAsync(d_ws, 0, zero_bytes, stream);

    k_deghist<<<ECHUNKS, 256, 0, stream>>>(edst, deg, labels, blockcnt, x_in, xw, W1, W2, wf);
    k_scancombo<<<SBLK + 1, 256, 0, stream>>>(deg, rowptr, dpart, blockcnt, coffs, ccount);
    k_dscan2<<<1, 256, 0, stream>>>(dpart, dbase, rowptr);
    k_cfill_dscan3<<<SBLK, 256, 0, stream>>>(rowptr, dbase, cursor, labels, coffs, clist);
    k_fill<<<ECHUNKS * 8, 256, 0, stream>>>(esrc, edst, cursor, adj);

    for (int t = 0; t < LL; t++) {
        for (int c = 0; c < CC; c++) {
            int tc = t * CC + c;
            int tpool = (c == 0) ? (t - 1) : -1;  // fuse previous layer's pool into gather
            k_gather<<<GIN_BLOCKS, 256, 0, stream>>>(
                xw, adj, rowptr, clist + c * NN, ccount + c, aggbuf, batch, z, tpool);
            k_lin1<<<MM_BLOCKS, 256, 0, stream>>>(
                aggbuf, ccount + c, wf + (size_t)tc * 4096, b1 + (size_t)tc * 64,
                h1buf, bnacc + (size_t)tc * NSHADOW * 128);
            k_cmfma<<<MM_BLOCKS, 256, 0, stream>>>(
                xw, clist + c * NN, ccount + c,
                g1 + (size_t)tc * 64, be1 + (size_t)tc * 64,
                wf + (size_t)(12 + tc) * 4096, b2 + (size_t)tc * 64,
                h1buf, bnacc + (size_t)tc * NSHADOW * 128);
        }
    }
    // last layer's pool (standalone)
    {
        int pool_waves = (NN + 63) / 64;
        int pool_blocks = (pool_waves * 64 + 255) / 256;
        k_pool<<<pool_blocks, 256, 0, stream>>>(xw, batch, z, LL - 1);
    }
    k_final1<<<GG, 256, 0, stream>>>(z, Wp1, bp1, hbuf);
    k_final2<<<1, 256, 0, stream>>>(hbuf, gp, bep, Wp2, bp2, out);
}